// Round 1
// baseline (278.646 us; speedup 1.0000x reference)
//
#include <hip/hip_runtime.h>
#include <hip/hip_bf16.h>
#include <stdint.h>

// ---------------------------------------------------------------------------
// HilbertAttention pipeline, bf16 MFMA implementation.
//   x   = ([q|k|v] @ [Wq;Wk;Wv]^T-transposed)/3          (GEMM1, K=1536)
//   qkv = x @ Wqkv                                        (GEMM2, N=1536)
//   attention: Hilbert-permuted, 128-seg, dilation 2 -> 4096 groups of 64x64
//   out = att @ Wout                                      (GEMM3, f32 out)
// All GEMMs: 128x128 tile, BK=64, 4 waves, mfma_f32_16x16x32_bf16,
// global_load_lds(16B) staging, XOR-swizzled LDS (conflict-free ds_read_b128).
// ---------------------------------------------------------------------------

typedef __bf16 bf16_t;
typedef __bf16 bf16x8 __attribute__((ext_vector_type(8)));
typedef float  f32x4  __attribute__((ext_vector_type(8/2)));

#define DEVI __device__ __forceinline__

static constexpr int Mtok = 16384;   // tokens per batch
static constexpr int ROWS = 32768;   // B * Mtok

DEVI void gload_lds16(const void* g, void* l) {
  __builtin_amdgcn_global_load_lds(
      (__attribute__((address_space(1))) uint32_t*)(uintptr_t)g,
      (__attribute__((address_space(3))) uint32_t*)(uint32_t)(uintptr_t)l,
      16, 0, 0);
}

// ---------------- Hilbert permutation (n = 128 grid) -----------------------
__global__ void k_perm(int* __restrict__ perm) {
  int d = blockIdx.x * 256 + threadIdx.x;
  if (d >= Mtok) return;
  int t = d, x = 0, y = 0;
  for (int s = 1; s < 128; s <<= 1) {
    int rx = (t >> 1) & 1;
    int ry = (t ^ rx) & 1;
    if (ry == 0) {
      if (rx == 1) { x = s - 1 - x; y = s - 1 - y; }
      int tmp = x; x = y; y = tmp;
    }
    x += s * rx;
    y += s * ry;
    t >>= 2;
  }
  perm[d] = y * 128 + x;
}

// ---------------- pack [q|k|v] rows into bf16 A0 [32768][1536] -------------
__global__ void k_prep_inputs(const float* __restrict__ q, const float* __restrict__ k,
                              const float* __restrict__ v, bf16_t* __restrict__ A0) {
  const int total = ROWS * 192;  // 16B-chunks of 8 bf16
  for (int e = blockIdx.x * blockDim.x + threadIdx.x; e < total; e += gridDim.x * blockDim.x) {
    int row = e / 192;
    int cc  = e % 192;
    const float* src = (cc < 64) ? q : (cc < 128 ? k : v);
    int c0 = (cc & 63) * 8;
    const float4* s4 = (const float4*)(src + (long)row * 512 + c0);
    float4 a = s4[0], b = s4[1];
    bf16x8 o;
    o[0] = (bf16_t)a.x; o[1] = (bf16_t)a.y; o[2] = (bf16_t)a.z; o[3] = (bf16_t)a.w;
    o[4] = (bf16_t)b.x; o[5] = (bf16_t)b.y; o[6] = (bf16_t)b.z; o[7] = (bf16_t)b.w;
    *(bf16x8*)(A0 + (long)e * 8) = o;
  }
}

// ---------------- transpose weights to bf16 B^T row-major ------------------
// W1t [512][1536]  = concat_K(Wq,Wk,Wv)^T / 3
// Wqkvt [1536][512] = Wqkv^T ;  Woutt [512][512] = Wout^T
__global__ void k_prep_w(const float* __restrict__ Wq, const float* __restrict__ Wk,
                         const float* __restrict__ Wv, const float* __restrict__ Wqkv,
                         const float* __restrict__ Wout,
                         bf16_t* __restrict__ W1t, bf16_t* __restrict__ Wqkvt,
                         bf16_t* __restrict__ Woutt) {
  const int tid = blockIdx.x * 256 + threadIdx.x;
  const int stride = gridDim.x * 256;
  for (int i = tid; i < 512 * 1536; i += stride) {
    int n = i / 1536, kk = i % 1536;
    const float* W = (kk < 512) ? Wq : (kk < 1024 ? Wk : Wv);
    W1t[i] = (bf16_t)(W[(kk & 511) * 512 + n] * (1.0f / 3.0f));
  }
  for (int i = tid; i < 1536 * 512; i += stride) {
    int n = i / 512, kk = i % 512;
    Wqkvt[i] = (bf16_t)Wqkv[kk * 1536 + n];
  }
  for (int i = tid; i < 512 * 512; i += stride) {
    int n = i / 512, kk = i % 512;
    Woutt[i] = (bf16_t)Wout[kk * 512 + n];
  }
}

// ---------------- GEMM: C[M,N] = A[M,K] @ Bt[N,K]^T ------------------------
// 128x128 tile, BK=64, 256 threads (4 waves in 2x2), single-buffered LDS.
template <bool OUTF32>
__global__ __launch_bounds__(256, 2) void k_gemm(const bf16_t* __restrict__ A,
                                                 const bf16_t* __restrict__ Bt,
                                                 bf16_t* __restrict__ Cb,
                                                 float* __restrict__ Cf,
                                                 int Ndim, int Kdim) {
  __shared__ bf16_t Alds[128 * 64];
  __shared__ bf16_t Blds[128 * 64];
  const int t = threadIdx.x;
  const int lane = t & 63, w = t >> 6;
  const int wr = w >> 1, wc = w & 1;
  const int l15 = lane & 15, l4 = lane >> 4;
  const long arow0 = (long)blockIdx.y * 128;
  const long brow0 = (long)blockIdx.x * 128;
  const bf16_t* Ab = A + arow0 * Kdim;
  const bf16_t* Bb = Bt + brow0 * Kdim;

  f32x4 acc[4][4] = {};

  for (int k0 = 0; k0 < Kdim; k0 += 64) {
#pragma unroll
    for (int rnd = 0; rnd < 4; rnd++) {
      int c = t + rnd * 256;          // 16B chunk id, 0..1023
      int row = c >> 3, cb = c & 7;   // 8 chunks per 128B row
      int cbs = cb ^ (row & 7);       // pre-swizzled global source (rule 21)
      gload_lds16(Ab + (long)row * Kdim + k0 + cbs * 8, Alds + c * 8);
      gload_lds16(Bb + (long)row * Kdim + k0 + cbs * 8, Blds + c * 8);
    }
    __syncthreads();
#pragma unroll
    for (int ks = 0; ks < 2; ks++) {
      bf16x8 af[4], bg[4];
#pragma unroll
      for (int m = 0; m < 4; m++) {
        int row = wr * 64 + m * 16 + l15;
        int cb = (ks * 4 + l4) ^ (row & 7);
        af[m] = *(const bf16x8*)(Alds + row * 64 + cb * 8);
      }
#pragma unroll
      for (int n = 0; n < 4; n++) {
        int row = wc * 64 + n * 16 + l15;
        int cb = (ks * 4 + l4) ^ (row & 7);
        bg[n] = *(const bf16x8*)(Blds + row * 64 + cb * 8);
      }
#pragma unroll
      for (int m = 0; m < 4; m++)
#pragma unroll
        for (int n = 0; n < 4; n++)
          acc[m][n] = __builtin_amdgcn_mfma_f32_16x16x32_bf16(af[m], bg[n], acc[m][n], 0, 0, 0);
    }
    __syncthreads();
  }

#pragma unroll
  for (int m = 0; m < 4; m++) {
#pragma unroll
    for (int n = 0; n < 4; n++) {
      long row = arow0 + wr * 64 + m * 16 + l4 * 4;
      long col = brow0 + wc * 64 + n * 16 + l15;
#pragma unroll
      for (int r = 0; r < 4; r++) {
        if constexpr (OUTF32) Cf[(row + r) * Ndim + col] = acc[m][n][r];
        else                  Cb[(row + r) * Ndim + col] = (bf16_t)acc[m][n][r];
      }
    }
  }
}

// ---------------- attention: one WG per (b, seg, head) ---------------------
// Per segment: 128 Hilbert-consecutive tokens, split into 2 dilation groups
// of 64. Wave w: group = w>>1, t-half = w&1 (rows t in [32*th, 32*th+32)).
// Q/K fragments load directly from global (gathered 64B segments).
// V transposed into swizzled LDS; P restaged via swizzled LDS; output
// staged in LDS and written as coalesced 128B row-chunks.
__global__ __launch_bounds__(256, 2) void k_attn(const bf16_t* __restrict__ QKV,
                                                 const int* __restrict__ perm,
                                                 bf16_t* __restrict__ ATT) {
  __shared__ bf16_t Vt[2][64 * 64];
  __shared__ bf16_t P[2][64 * 64];
  __shared__ bf16_t O[128 * 64];
  __shared__ int perml[128];
  const int n = blockIdx.x, h = blockIdx.y, b = blockIdx.z;
  const int t = threadIdx.x;
  const int lane = t & 63, w = t >> 6;
  const int l15 = lane & 15, l4 = lane >> 4;

  if (t < 128) perml[t] = perm[n * 128 + t];
  __syncthreads();

  // ---- gather V, transposed: Vt[grp][d][s] (row=d 128B, XOR-swizzled) ----
#pragma unroll
  for (int it = 0; it < 4; it++) {
    int c = t + it * 256;           // 0..1023
    int tok = c >> 3, c8 = c & 7;   // token-local, 8-elem chunk of d
    long j = (long)b * Mtok + perml[tok];
    bf16x8 vv = *(const bf16x8*)(QKV + j * 1536 + 1024 + h * 64 + c8 * 8);
    int grp = tok & 1, s = tok >> 1;
    bf16_t* vt = Vt[grp];
#pragma unroll
    for (int i = 0; i < 8; i++) {
      int d = c8 * 8 + i;
      vt[d * 64 + (s ^ ((d & 7) << 3))] = vv[i];
    }
  }

  const int grp = w >> 1, th = w & 1;

  // ---- QK^T : scores[t][s], fragments direct from global ----
  f32x4 sc[2][4] = {};
#pragma unroll
  for (int ks = 0; ks < 2; ks++) {
    bf16x8 aq[2], bk[4];
#pragma unroll
    for (int tf = 0; tf < 2; tf++) {
      int tq = th * 32 + tf * 16 + l15;
      long j = (long)b * Mtok + perml[tq * 2 + grp];
      aq[tf] = *(const bf16x8*)(QKV + j * 1536 + h * 64 + ks * 32 + l4 * 8);
    }
#pragma unroll
    for (int sf = 0; sf < 4; sf++) {
      int s = sf * 16 + l15;
      long j = (long)b * Mtok + perml[s * 2 + grp];
      bk[sf] = *(const bf16x8*)(QKV + j * 1536 + 512 + h * 64 + ks * 32 + l4 * 8);
    }
#pragma unroll
    for (int tf = 0; tf < 2; tf++)
#pragma unroll
      for (int sf = 0; sf < 4; sf++)
        sc[tf][sf] = __builtin_amdgcn_mfma_f32_16x16x32_bf16(aq[tf], bk[sf], sc[tf][sf], 0, 0, 0);
  }

  // ---- softmax over s (64), wave-parallel 16-lane reductions ----
  const float scale = 0.125f;  // 1/sqrt(64)
#pragma unroll
  for (int tf = 0; tf < 2; tf++) {
#pragma unroll
    for (int r = 0; r < 4; r++) {
      float mx = fmaxf(fmaxf(sc[tf][0][r], sc[tf][1][r]), fmaxf(sc[tf][2][r], sc[tf][3][r]));
      mx = fmaxf(mx, __shfl_xor(mx, 1, 64));
      mx = fmaxf(mx, __shfl_xor(mx, 2, 64));
      mx = fmaxf(mx, __shfl_xor(mx, 4, 64));
      mx = fmaxf(mx, __shfl_xor(mx, 8, 64));
      float p0 = __expf((sc[tf][0][r] - mx) * scale);
      float p1 = __expf((sc[tf][1][r] - mx) * scale);
      float p2 = __expf((sc[tf][2][r] - mx) * scale);
      float p3 = __expf((sc[tf][3][r] - mx) * scale);
      float sum = p0 + p1 + p2 + p3;
      sum += __shfl_xor(sum, 1, 64);
      sum += __shfl_xor(sum, 2, 64);
      sum += __shfl_xor(sum, 4, 64);
      sum += __shfl_xor(sum, 8, 64);
      float inv = 1.0f / sum;
      int trow = th * 32 + tf * 16 + l4 * 4 + r;
      int sw = (trow & 7) << 3;
      bf16_t* pp = P[grp];
      pp[trow * 64 + ((l15     ) ^ sw)] = (bf16_t)(p0 * inv);
      pp[trow * 64 + ((l15 + 16) ^ sw)] = (bf16_t)(p1 * inv);
      pp[trow * 64 + ((l15 + 32) ^ sw)] = (bf16_t)(p2 * inv);
      pp[trow * 64 + ((l15 + 48) ^ sw)] = (bf16_t)(p3 * inv);
    }
  }
  __syncthreads();  // P + Vt visible to all

  // ---- PV : out[t][d] ----
  f32x4 oacc[2][4] = {};
#pragma unroll
  for (int ks = 0; ks < 2; ks++) {
    bf16x8 ap[2], bv[4];
#pragma unroll
    for (int tf = 0; tf < 2; tf++) {
      int trow = th * 32 + tf * 16 + l15;
      int cb = (ks * 4 + l4) ^ (trow & 7);
      ap[tf] = *(const bf16x8*)(P[grp] + trow * 64 + cb * 8);
    }
#pragma unroll
    for (int df = 0; df < 4; df++) {
      int d = df * 16 + l15;
      int cb = (ks * 4 + l4) ^ (d & 7);
      bv[df] = *(const bf16x8*)(Vt[grp] + d * 64 + cb * 8);
    }
#pragma unroll
    for (int tf = 0; tf < 2; tf++)
#pragma unroll
      for (int df = 0; df < 4; df++)
        oacc[tf][df] = __builtin_amdgcn_mfma_f32_16x16x32_bf16(ap[tf], bv[df], oacc[tf][df], 0, 0, 0);
  }

  // ---- stage output rows in LDS, then coalesced scatter (128B chunks) ----
#pragma unroll
  for (int tf = 0; tf < 2; tf++)
#pragma unroll
    for (int df = 0; df < 4; df++)
#pragma unroll
      for (int r = 0; r < 4; r++) {
        int trow = th * 32 + tf * 16 + l4 * 4 + r;
        int tok = trow * 2 + grp;   // position within segment (PERM order)
        O[tok * 64 + df * 16 + l15] = (bf16_t)oacc[tf][df][r];
      }
  __syncthreads();
#pragma unroll
  for (int it = 0; it < 4; it++) {
    int c = t + it * 256;
    int tok = c >> 3, c8 = c & 7;
    long j = (long)b * Mtok + perml[tok];  // inverse-permute == scatter to PERM[i]
    *(bf16x8*)(ATT + j * 512 + h * 64 + c8 * 8) = *(const bf16x8*)(O + tok * 64 + c8 * 8);
  }
}

// ---------------------------------------------------------------------------
extern "C" void kernel_launch(void* const* d_in, const int* in_sizes, int n_in,
                              void* d_out, int out_size, void* d_ws, size_t ws_size,
                              hipStream_t stream) {
  const float* q    = (const float*)d_in[0];
  const float* k    = (const float*)d_in[1];
  const float* v    = (const float*)d_in[2];
  const float* Wq   = (const float*)d_in[3];
  const float* Wk   = (const float*)d_in[4];
  const float* Wv   = (const float*)d_in[5];
  const float* Wqkv = (const float*)d_in[6];
  const float* Wout = (const float*)d_in[7];

  char* ws = (char*)d_ws;
  const size_t QKV_BYTES = (size_t)ROWS * 1536 * 2;  // 100,663,296
  const size_t X_BYTES   = (size_t)ROWS * 512 * 2;   //  33,554,432
  bf16_t* QKV   = (bf16_t*)ws;                        // also A0 (dead after GEMM1)
  bf16_t* X     = (bf16_t*)(ws + QKV_BYTES);          // also ATT (X dead after GEMM2)
  bf16_t* W1t   = (bf16_t*)(ws + QKV_BYTES + X_BYTES);
  bf16_t* Wqkvt = W1t + 512 * 1536;
  bf16_t* Woutt = Wqkvt + 1536 * 512;
  int*    perm  = (int*)(Woutt + 512 * 512);

  k_perm<<<64, 256, 0, stream>>>(perm);
  k_prep_inputs<<<2048, 256, 0, stream>>>(q, k, v, QKV);  // A0 aliases QKV
  k_prep_w<<<512, 256, 0, stream>>>(Wq, Wk, Wv, Wqkv, Wout, W1t, Wqkvt, Woutt);
  // GEMM1: X = A0 @ W1  (M=32768, N=512, K=1536), 1/3 folded into W1t
  k_gemm<false><<<dim3(4, 256), 256, 0, stream>>>(QKV, W1t, X, nullptr, 512, 1536);
  // GEMM2: QKV = X @ Wqkv (N=1536, K=512)
  k_gemm<false><<<dim3(12, 256), 256, 0, stream>>>(X, Wqkvt, QKV, nullptr, 1536, 512);
  // attention: reads QKV, writes ATT (aliases X)
  k_attn<<<dim3(128, 8, 2), 256, 0, stream>>>(QKV, perm, X);
  // GEMM3: out = ATT @ Wout (f32 output)
  k_gemm<true><<<dim3(4, 256), 256, 0, stream>>>(X, Woutt, nullptr, (float*)d_out, 512, 512);
}

// Round 2
// 272.749 us; speedup vs baseline: 1.0216x; 1.0216x over previous
//
#include <hip/hip_runtime.h>
#include <hip/hip_bf16.h>
#include <stdint.h>

// ---------------------------------------------------------------------------
// HilbertAttention pipeline, bf16 MFMA implementation.
//   x   = ([q|k|v] @ W1t^T)/3        (GEMM1, M=32768, N=512,  K=1536)
//   qkv = x @ Wqkvt^T                (GEMM2, M=32768, N=1536, K=512)
//   attention (Hilbert, 128-seg, dil 2 -> 4096 groups of 64x64)
//   out = att @ Woutt^T  (f32 out)   (GEMM3, M=32768, N=512,  K=512)
// GEMMs: 256x256 tile, BK=64, 8 waves (2Mx4N), ring-2 LDS double-buffer,
// 4-phase per K-tile with counted s_waitcnt vmcnt(4) (T3+T4), setprio (T5),
// XOR-swizzled LDS via pre-swizzled global_load_lds source (T2, rule 21).
// ---------------------------------------------------------------------------

typedef __bf16 bf16_t;
typedef __bf16 bf16x8 __attribute__((ext_vector_type(8)));
typedef float  f32x4  __attribute__((ext_vector_type(4)));

#define DEVI __device__ __forceinline__
#define SFENCE __builtin_amdgcn_sched_barrier(0)

static constexpr int Mtok = 16384;   // tokens per batch
static constexpr int ROWS = 32768;   // B * Mtok

DEVI void gload_lds16(const void* g, void* l) {
  __builtin_amdgcn_global_load_lds(
      (__attribute__((address_space(1))) uint32_t*)(uintptr_t)g,
      (__attribute__((address_space(3))) uint32_t*)(uint32_t)(uintptr_t)l,
      16, 0, 0);
}

// ---------------- Hilbert permutation (n = 128 grid) -----------------------
__global__ void k_perm(int* __restrict__ perm) {
  int d = blockIdx.x * 256 + threadIdx.x;
  if (d >= Mtok) return;
  int t = d, x = 0, y = 0;
  for (int s = 1; s < 128; s <<= 1) {
    int rx = (t >> 1) & 1;
    int ry = (t ^ rx) & 1;
    if (ry == 0) {
      if (rx == 1) { x = s - 1 - x; y = s - 1 - y; }
      int tmp = x; x = y; y = tmp;
    }
    x += s * rx;
    y += s * ry;
    t >>= 2;
  }
  perm[d] = y * 128 + x;
}

// ---------------- pack [q|k|v] rows into bf16 A0 [32768][1536] -------------
__global__ void k_prep_inputs(const float* __restrict__ q, const float* __restrict__ k,
                              const float* __restrict__ v, bf16_t* __restrict__ A0) {
  const int total = ROWS * 192;  // 16B-chunks of 8 bf16
  for (int e = blockIdx.x * blockDim.x + threadIdx.x; e < total; e += gridDim.x * blockDim.x) {
    int row = e / 192;
    int cc  = e % 192;
    const float* src = (cc < 64) ? q : (cc < 128 ? k : v);
    int c0 = (cc & 63) * 8;
    const float4* s4 = (const float4*)(src + (long)row * 512 + c0);
    float4 a = s4[0], b = s4[1];
    bf16x8 o;
    o[0] = (bf16_t)a.x; o[1] = (bf16_t)a.y; o[2] = (bf16_t)a.z; o[3] = (bf16_t)a.w;
    o[4] = (bf16_t)b.x; o[5] = (bf16_t)b.y; o[6] = (bf16_t)b.z; o[7] = (bf16_t)b.w;
    *(bf16x8*)(A0 + (long)e * 8) = o;
  }
}

// ---------------- transpose weights to bf16 B^T row-major ------------------
__global__ void k_prep_w(const float* __restrict__ Wq, const float* __restrict__ Wk,
                         const float* __restrict__ Wv, const float* __restrict__ Wqkv,
                         const float* __restrict__ Wout,
                         bf16_t* __restrict__ W1t, bf16_t* __restrict__ Wqkvt,
                         bf16_t* __restrict__ Woutt) {
  const int tid = blockIdx.x * 256 + threadIdx.x;
  const int stride = gridDim.x * 256;
  for (int i = tid; i < 512 * 1536; i += stride) {
    int n = i / 1536, kk = i % 1536;
    const float* W = (kk < 512) ? Wq : (kk < 1024 ? Wk : Wv);
    W1t[i] = (bf16_t)(W[(kk & 511) * 512 + n] * (1.0f / 3.0f));
  }
  for (int i = tid; i < 1536 * 512; i += stride) {
    int n = i / 512, kk = i % 512;
    Wqkvt[i] = (bf16_t)Wqkv[kk * 1536 + n];
  }
  for (int i = tid; i < 512 * 512; i += stride) {
    int n = i / 512, kk = i % 512;
    Woutt[i] = (bf16_t)Wout[kk * 512 + n];
  }
}

// ---------------- 256x256 GEMM, 4-phase pipelined --------------------------
// C[M,N] = A[M,K] @ Bt[N,K]^T. 512 threads = 8 waves (wm in 0..1, wn in 0..3),
// per-wave output 128x64 (acc[8][4]). LDS: ring-2 of (A 256x64 + B 256x64).
// Stage units (128 rows each, 2 global_load_lds per thread):
//   A-q0 = rows {0-63,128-191}   (read only in QM=0 phases)
//   A-q1 = rows {64-127,192-255} (read only in QM=1 phases)
//   B-q0 = rows {r: bit5=0}      (read only in QN=0 phases)
//   B-q1 = rows {r: bit5=1}      (read only in QN=1 phases)
// Phase p of tile t stages: P1:(t+1).Aq1->nxt  P2:(t+1).Bq1->nxt
//                           P3:(t+2).Aq0->cur  P4:(t+2).Bq0->cur
// (each issue is after the barrier closing the last read of that region).
// Boundary wait: vmcnt(4) = the 2 stage-units issued in P3/P4. Never 0 in
// steady state (T4).

DEVI void stageA(const bf16_t* Ab, int Kdim, int k0, bf16_t* dst, int qsel,
                 int tid, int cswz) {
  int r = tid >> 3;
  int row0 = r + qsel * 64;
  const bf16_t* g = Ab + (long)row0 * Kdim + k0 + cswz * 8;
  gload_lds16(g, dst + row0 * 64 + (tid & 7) * 8);
  gload_lds16(g + (long)128 * Kdim, dst + (row0 + 128) * 64 + (tid & 7) * 8);
}

DEVI void stageB(const bf16_t* Bb, int Kdim, int k0, bf16_t* dst, int qsel,
                 int tid, int cswz) {
  int r = tid >> 3;
  int rb0 = (r >> 5) * 64 + qsel * 32 + (r & 31);
  const bf16_t* g = Bb + (long)rb0 * Kdim + k0 + cswz * 8;
  gload_lds16(g, dst + rb0 * 64 + (tid & 7) * 8);
  gload_lds16(g + (long)128 * Kdim, dst + (rb0 + 128) * 64 + (tid & 7) * 8);
}

#define PHASE(QM, QN, STAGE_STMT, TAIL_STMT)                                   \
  do {                                                                         \
    bf16x8 af[4][2], bg[2][2];                                                 \
    _Pragma("unroll") for (int m = 0; m < 4; m++) {                            \
      int row = wm * 128 + (QM) * 64 + m * 16 + l15;                           \
      af[m][0] = *(const bf16x8*)(Acur + row * 64 + cb0 * 8);                  \
      af[m][1] = *(const bf16x8*)(Acur + row * 64 + cb1 * 8);                  \
    }                                                                          \
    _Pragma("unroll") for (int n = 0; n < 2; n++) {                            \
      int row = wn * 64 + (QN) * 32 + n * 16 + l15;                            \
      bg[n][0] = *(const bf16x8*)(Bcur + row * 64 + cb0 * 8);                  \
      bg[n][1] = *(const bf16x8*)(Bcur + row * 64 + cb1 * 8);                  \
    }                                                                          \
    STAGE_STMT;                                                                \
    SFENCE; __builtin_amdgcn_s_barrier(); SFENCE;                              \
    __builtin_amdgcn_s_setprio(1);                                             \
    _Pragma("unroll") for (int m = 0; m < 4; m++)                              \
    _Pragma("unroll") for (int n = 0; n < 2; n++) {                            \
      acc[(QM)*4+m][(QN)*2+n] = __builtin_amdgcn_mfma_f32_16x16x32_bf16(       \
          af[m][0], bg[n][0], acc[(QM)*4+m][(QN)*2+n], 0, 0, 0);               \
      acc[(QM)*4+m][(QN)*2+n] = __builtin_amdgcn_mfma_f32_16x16x32_bf16(       \
          af[m][1], bg[n][1], acc[(QM)*4+m][(QN)*2+n], 0, 0, 0);               \
    }                                                                          \
    __builtin_amdgcn_s_setprio(0);                                             \
    TAIL_STMT;                                                                 \
    SFENCE; __builtin_amdgcn_s_barrier(); SFENCE;                              \
  } while (0)

template <bool OUTF32>
__global__ __launch_bounds__(512, 2) void k_gemm256(const bf16_t* __restrict__ A,
                                                    const bf16_t* __restrict__ Bt,
                                                    bf16_t* __restrict__ Cb,
                                                    float* __restrict__ Cf,
                                                    int Ndim, int Kdim) {
  __shared__ bf16_t lds[4 * 16384];  // 128 KiB: A0 | B0 | A1 | B1
  const int tid = threadIdx.x;
  const int lane = tid & 63, w = tid >> 6;
  const int wm = w >> 2, wn = w & 3;
  const int l15 = lane & 15, l4 = lane >> 4;
  const int cb0 = l4 ^ (l15 & 7), cb1 = cb0 ^ 4;
  const int cswz = (tid & 7) ^ ((tid >> 3) & 7);
  const long arow0 = (long)blockIdx.y * 256;
  const long bcol0 = (long)blockIdx.x * 256;
  const bf16_t* Ab = A + arow0 * Kdim;
  const bf16_t* Bb = Bt + bcol0 * Kdim;
  const int NT = Kdim >> 6;

  bf16_t* Acur = lds;
  bf16_t* Bcur = lds + 16384;
  bf16_t* Anxt = lds + 32768;
  bf16_t* Bnxt = lds + 49152;

  f32x4 acc[8][4] = {};

  // prologue: tile0 complete + tile1 {Aq0,Bq0}; wait so tile0 landed.
  stageA(Ab, Kdim, 0, Acur, 0, tid, cswz);
  stageB(Bb, Kdim, 0, Bcur, 0, tid, cswz);
  stageA(Ab, Kdim, 0, Acur, 1, tid, cswz);
  stageB(Bb, Kdim, 0, Bcur, 1, tid, cswz);
  stageA(Ab, Kdim, 64, Anxt, 0, tid, cswz);
  stageB(Bb, Kdim, 64, Bnxt, 0, tid, cswz);
  asm volatile("s_waitcnt vmcnt(4)" ::: "memory");
  __builtin_amdgcn_s_barrier();
  SFENCE;

  for (int t = 0; t < NT; t++) {
    PHASE(0, 0, if (t + 1 < NT) stageA(Ab, Kdim, (t + 1) * 64, Anxt, 1, tid, cswz), );
    PHASE(0, 1, if (t + 1 < NT) stageB(Bb, Kdim, (t + 1) * 64, Bnxt, 1, tid, cswz), );
    PHASE(1, 0, if (t + 2 < NT) stageA(Ab, Kdim, (t + 2) * 64, Acur, 0, tid, cswz), );
    PHASE(1, 1, if (t + 2 < NT) stageB(Bb, Kdim, (t + 2) * 64, Bcur, 0, tid, cswz),
          if (t + 2 < NT) { asm volatile("s_waitcnt vmcnt(4)" ::: "memory"); }
          else            { asm volatile("s_waitcnt vmcnt(0)" ::: "memory"); });
    bf16_t* tA = Acur; Acur = Anxt; Anxt = tA;
    bf16_t* tB = Bcur; Bcur = Bnxt; Bnxt = tB;
  }

  // epilogue: C-write
#pragma unroll
  for (int i = 0; i < 8; i++) {
#pragma unroll
    for (int j = 0; j < 4; j++) {
      long row = arow0 + wm * 128 + i * 16 + l4 * 4;
      long col = bcol0 + wn * 64 + j * 16 + l15;
#pragma unroll
      for (int r = 0; r < 4; r++) {
        if constexpr (OUTF32) Cf[(row + r) * Ndim + col] = acc[i][j][r];
        else                  Cb[(row + r) * Ndim + col] = (bf16_t)acc[i][j][r];
      }
    }
  }
}

// ---------------- attention: one WG per (b, seg, head) ---------------------
__global__ __launch_bounds__(256, 2) void k_attn(const bf16_t* __restrict__ QKV,
                                                 const int* __restrict__ perm,
                                                 bf16_t* __restrict__ ATT) {
  __shared__ bf16_t Vt[2][64 * 64];
  __shared__ bf16_t P[2][64 * 64];
  __shared__ bf16_t O[128 * 64];
  __shared__ int perml[128];
  const int n = blockIdx.x, h = blockIdx.y, b = blockIdx.z;
  const int t = threadIdx.x;
  const int lane = t & 63, w = t >> 6;
  const int l15 = lane & 15, l4 = lane >> 4;

  if (t < 128) perml[t] = perm[n * 128 + t];
  __syncthreads();

  // ---- gather V, transposed: Vt[grp][d][s] (row=d 128B, XOR-swizzled) ----
#pragma unroll
  for (int it = 0; it < 4; it++) {
    int c = t + it * 256;           // 0..1023
    int tok = c >> 3, c8 = c & 7;   // token-local, 8-elem chunk of d
    long j = (long)b * Mtok + perml[tok];
    bf16x8 vv = *(const bf16x8*)(QKV + j * 1536 + 1024 + h * 64 + c8 * 8);
    int grp = tok & 1, s = tok >> 1;
    bf16_t* vt = Vt[grp];
#pragma unroll
    for (int i = 0; i < 8; i++) {
      int d = c8 * 8 + i;
      vt[d * 64 + (s ^ ((d & 7) << 3))] = vv[i];
    }
  }

  const int grp = w >> 1, th = w & 1;

  // ---- QK^T : scores[t][s], fragments direct from global ----
  f32x4 sc[2][4] = {};
#pragma unroll
  for (int ks = 0; ks < 2; ks++) {
    bf16x8 aq[2], bk[4];
#pragma unroll
    for (int tf = 0; tf < 2; tf++) {
      int tq = th * 32 + tf * 16 + l15;
      long j = (long)b * Mtok + perml[tq * 2 + grp];
      aq[tf] = *(const bf16x8*)(QKV + j * 1536 + h * 64 + ks * 32 + l4 * 8);
    }
#pragma unroll
    for (int sf = 0; sf < 4; sf++) {
      int s = sf * 16 + l15;
      long j = (long)b * Mtok + perml[s * 2 + grp];
      bk[sf] = *(const bf16x8*)(QKV + j * 1536 + 512 + h * 64 + ks * 32 + l4 * 8);
    }
#pragma unroll
    for (int tf = 0; tf < 2; tf++)
#pragma unroll
      for (int sf = 0; sf < 4; sf++)
        sc[tf][sf] = __builtin_amdgcn_mfma_f32_16x16x32_bf16(aq[tf], bk[sf], sc[tf][sf], 0, 0, 0);
  }

  // ---- softmax over s (64), wave-parallel 16-lane reductions ----
  const float scale = 0.125f;  // 1/sqrt(64)
#pragma unroll
  for (int tf = 0; tf < 2; tf++) {
#pragma unroll
    for (int r = 0; r < 4; r++) {
      float mx = fmaxf(fmaxf(sc[tf][0][r], sc[tf][1][r]), fmaxf(sc[tf][2][r], sc[tf][3][r]));
      mx = fmaxf(mx, __shfl_xor(mx, 1, 64));
      mx = fmaxf(mx, __shfl_xor(mx, 2, 64));
      mx = fmaxf(mx, __shfl_xor(mx, 4, 64));
      mx = fmaxf(mx, __shfl_xor(mx, 8, 64));
      float p0 = __expf((sc[tf][0][r] - mx) * scale);
      float p1 = __expf((sc[tf][1][r] - mx) * scale);
      float p2 = __expf((sc[tf][2][r] - mx) * scale);
      float p3 = __expf((sc[tf][3][r] - mx) * scale);
      float sum = p0 + p1 + p2 + p3;
      sum += __shfl_xor(sum, 1, 64);
      sum += __shfl_xor(sum, 2, 64);
      sum += __shfl_xor(sum, 4, 64);
      sum += __shfl_xor(sum, 8, 64);
      float inv = 1.0f / sum;
      int trow = th * 32 + tf * 16 + l4 * 4 + r;
      int sw = (trow & 7) << 3;
      bf16_t* pp = P[grp];
      pp[trow * 64 + ((l15     ) ^ sw)] = (bf16_t)(p0 * inv);
      pp[trow * 64 + ((l15 + 16) ^ sw)] = (bf16_t)(p1 * inv);
      pp[trow * 64 + ((l15 + 32) ^ sw)] = (bf16_t)(p2 * inv);
      pp[trow * 64 + ((l15 + 48) ^ sw)] = (bf16_t)(p3 * inv);
    }
  }
  __syncthreads();  // P + Vt visible to all

  // ---- PV : out[t][d] ----
  f32x4 oacc[2][4] = {};
#pragma unroll
  for (int ks = 0; ks < 2; ks++) {
    bf16x8 ap[2], bv[4];
#pragma unroll
    for (int tf = 0; tf < 2; tf++) {
      int trow = th * 32 + tf * 16 + l15;
      int cb = (ks * 4 + l4) ^ (trow & 7);
      ap[tf] = *(const bf16x8*)(P[grp] + trow * 64 + cb * 8);
    }
#pragma unroll
    for (int df = 0; df < 4; df++) {
      int d = df * 16 + l15;
      int cb = (ks * 4 + l4) ^ (d & 7);
      bv[df] = *(const bf16x8*)(Vt[grp] + d * 64 + cb * 8);
    }
#pragma unroll
    for (int tf = 0; tf < 2; tf++)
#pragma unroll
      for (int df = 0; df < 4; df++)
        oacc[tf][df] = __builtin_amdgcn_mfma_f32_16x16x32_bf16(ap[tf], bv[df], oacc[tf][df], 0, 0, 0);
  }

  // ---- stage output rows in LDS, then coalesced scatter (128B chunks) ----
#pragma unroll
  for (int tf = 0; tf < 2; tf++)
#pragma unroll
    for (int df = 0; df < 4; df++)
#pragma unroll
      for (int r = 0; r < 4; r++) {
        int trow = th * 32 + tf * 16 + l4 * 4 + r;
        int tok = trow * 2 + grp;   // position within segment (PERM order)
        O[tok * 64 + df * 16 + l15] = (bf16_t)oacc[tf][df][r];
      }
  __syncthreads();
#pragma unroll
  for (int it = 0; it < 4; it++) {
    int c = t + it * 256;
    int tok = c >> 3, c8 = c & 7;
    long j = (long)b * Mtok + perml[tok];  // inverse-permute == scatter to PERM[i]
    *(bf16x8*)(ATT + j * 512 + h * 64 + c8 * 8) = *(const bf16x8*)(O + tok * 64 + c8 * 8);
  }
}

// ---------------------------------------------------------------------------
extern "C" void kernel_launch(void* const* d_in, const int* in_sizes, int n_in,
                              void* d_out, int out_size, void* d_ws, size_t ws_size,
                              hipStream_t stream) {
  const float* q    = (const float*)d_in[0];
  const float* k    = (const float*)d_in[1];
  const float* v    = (const float*)d_in[2];
  const float* Wq   = (const float*)d_in[3];
  const float* Wk   = (const float*)d_in[4];
  const float* Wv   = (const float*)d_in[5];
  const float* Wqkv = (const float*)d_in[6];
  const float* Wout = (const float*)d_in[7];

  char* ws = (char*)d_ws;
  const size_t QKV_BYTES = (size_t)ROWS * 1536 * 2;  // 100,663,296
  const size_t X_BYTES   = (size_t)ROWS * 512 * 2;   //  33,554,432
  bf16_t* QKV   = (bf16_t*)ws;                        // also A0 (dead after GEMM1)
  bf16_t* X     = (bf16_t*)(ws + QKV_BYTES);          // also ATT (X dead after GEMM2)
  bf16_t* W1t   = (bf16_t*)(ws + QKV_BYTES + X_BYTES);
  bf16_t* Wqkvt = W1t + 512 * 1536;
  bf16_t* Woutt = Wqkvt + 1536 * 512;
  int*    perm  = (int*)(Woutt + 512 * 512);

  k_perm<<<64, 256, 0, stream>>>(perm);
  k_prep_inputs<<<2048, 256, 0, stream>>>(q, k, v, QKV);  // A0 aliases QKV
  k_prep_w<<<512, 256, 0, stream>>>(Wq, Wk, Wv, Wqkv, Wout, W1t, Wqkvt, Woutt);
  // GEMM1: X = A0 @ W1  (M=32768, N=512, K=1536), 1/3 folded into W1t
  k_gemm256<false><<<dim3(2, 128), 512, 0, stream>>>(QKV, W1t, X, nullptr, 512, 1536);
  // GEMM2: QKV = X @ Wqkv (N=1536, K=512)
  k_gemm256<false><<<dim3(6, 128), 512, 0, stream>>>(X, Wqkvt, QKV, nullptr, 1536, 512);
  // attention: reads QKV, writes ATT (aliases X)
  k_attn<<<dim3(128, 8, 2), 256, 0, stream>>>(QKV, perm, X);
  // GEMM3: out = ATT @ Wout (f32 output)
  k_gemm256<true><<<dim3(2, 128), 512, 0, stream>>>(X, Woutt, nullptr, (float*)d_out, 512, 512);
}

// Round 3
// 233.912 us; speedup vs baseline: 1.1912x; 1.1660x over previous
//
#include <hip/hip_runtime.h>
#include <hip/hip_bf16.h>
#include <stdint.h>

// ---------------------------------------------------------------------------
// HilbertAttention pipeline, bf16 MFMA implementation.
//   x   = ([q|k|v] @ W1t^T)/3        (GEMM1 fused f32->bf16 A-staging,
//                                     M=32768, N=512, K=1536 over q,k,v)
//   qkv = x @ Wqkvt^T                (GEMM2, M=32768, N=1536, K=512)
//   attention (Hilbert, 128-seg, dil 2 -> 4096 groups of 64x64)
//   out = att @ Woutt^T  (f32 out)   (GEMM3, M=32768, N=512,  K=512)
// GEMMs: 256x256 tile, BK=64, 8 waves (2Mx4N), ring-2 LDS double-buffer,
// 4-phase per K-tile with counted s_waitcnt vmcnt (T3+T4), setprio (T5),
// XOR-swizzled LDS (T2). GEMM1 reg-stages A from f32 q/k/v (T14 split:
// write prev tile's regs early-phase, issue t+2 loads after; compiler
// tracks the reg dataflow, manual vmcnt only counts the B gload_lds).
// ---------------------------------------------------------------------------

typedef __bf16 bf16_t;
typedef __bf16 bf16x8 __attribute__((ext_vector_type(8)));
typedef float  f32x4  __attribute__((ext_vector_type(4)));

#define DEVI __device__ __forceinline__
#define SFENCE __builtin_amdgcn_sched_barrier(0)

static constexpr int Mtok = 16384;   // tokens per batch
static constexpr int ROWS = 32768;   // B * Mtok

DEVI void gload_lds16(const void* g, void* l) {
  __builtin_amdgcn_global_load_lds(
      (__attribute__((address_space(1))) uint32_t*)(uintptr_t)g,
      (__attribute__((address_space(3))) uint32_t*)(uint32_t)(uintptr_t)l,
      16, 0, 0);
}

// ---------------- Hilbert permutation (n = 128 grid) -----------------------
__global__ void k_perm(int* __restrict__ perm) {
  int d = blockIdx.x * 256 + threadIdx.x;
  if (d >= Mtok) return;
  int t = d, x = 0, y = 0;
  for (int s = 1; s < 128; s <<= 1) {
    int rx = (t >> 1) & 1;
    int ry = (t ^ rx) & 1;
    if (ry == 0) {
      if (rx == 1) { x = s - 1 - x; y = s - 1 - y; }
      int tmp = x; x = y; y = tmp;
    }
    x += s * rx;
    y += s * ry;
    t >>= 2;
  }
  perm[d] = y * 128 + x;
}

// ---------------- transpose weights to bf16 B^T row-major ------------------
__global__ void k_prep_w(const float* __restrict__ Wq, const float* __restrict__ Wk,
                         const float* __restrict__ Wv, const float* __restrict__ Wqkv,
                         const float* __restrict__ Wout,
                         bf16_t* __restrict__ W1t, bf16_t* __restrict__ Wqkvt,
                         bf16_t* __restrict__ Woutt) {
  const int tid = blockIdx.x * 256 + threadIdx.x;
  const int stride = gridDim.x * 256;
  for (int i = tid; i < 512 * 1536; i += stride) {
    int n = i / 1536, kk = i % 1536;
    const float* W = (kk < 512) ? Wq : (kk < 1024 ? Wk : Wv);
    W1t[i] = (bf16_t)(W[(kk & 511) * 512 + n] * (1.0f / 3.0f));
  }
  for (int i = tid; i < 1536 * 512; i += stride) {
    int n = i / 512, kk = i % 512;
    Wqkvt[i] = (bf16_t)Wqkv[kk * 1536 + n];
  }
  for (int i = tid; i < 512 * 512; i += stride) {
    int n = i / 512, kk = i % 512;
    Woutt[i] = (bf16_t)Wout[kk * 512 + n];
  }
}

// ---------------- shared staging helpers -----------------------------------
DEVI void stageB(const bf16_t* Bb, int Kdim, int k0, bf16_t* dst, int qsel,
                 int tid, int cswz) {
  int r = tid >> 3;
  int rb0 = (r >> 5) * 64 + qsel * 32 + (r & 31);
  const bf16_t* g = Bb + (long)rb0 * Kdim + k0 + cswz * 8;
  gload_lds16(g, dst + rb0 * 64 + (tid & 7) * 8);
  gload_lds16(g + (long)128 * Kdim, dst + (rb0 + 128) * 64 + (tid & 7) * 8);
}

DEVI void stageA(const bf16_t* Ab, int Kdim, int k0, bf16_t* dst, int qsel,
                 int tid, int cswz) {
  int r = tid >> 3;
  int row0 = r + qsel * 64;
  const bf16_t* g = Ab + (long)row0 * Kdim + k0 + cswz * 8;
  gload_lds16(g, dst + row0 * 64 + (tid & 7) * 8);
  gload_lds16(g + (long)128 * Kdim, dst + (row0 + 128) * 64 + (tid & 7) * 8);
}

// ---------------- generic 256x256 GEMM (bf16 A in memory) ------------------
#define PHASE(QM, QN, STAGE_STMT, TAIL_STMT)                                   \
  do {                                                                         \
    bf16x8 af[4][2], bg[2][2];                                                 \
    _Pragma("unroll") for (int m = 0; m < 4; m++) {                            \
      int row = wm * 128 + (QM) * 64 + m * 16 + l15;                           \
      af[m][0] = *(const bf16x8*)(Acur + row * 64 + cb0 * 8);                  \
      af[m][1] = *(const bf16x8*)(Acur + row * 64 + cb1 * 8);                  \
    }                                                                          \
    _Pragma("unroll") for (int n = 0; n < 2; n++) {                            \
      int row = wn * 64 + (QN) * 32 + n * 16 + l15;                            \
      bg[n][0] = *(const bf16x8*)(Bcur + row * 64 + cb0 * 8);                  \
      bg[n][1] = *(const bf16x8*)(Bcur + row * 64 + cb1 * 8);                  \
    }                                                                          \
    STAGE_STMT;                                                                \
    SFENCE; __builtin_amdgcn_s_barrier(); SFENCE;                              \
    __builtin_amdgcn_s_setprio(1);                                             \
    _Pragma("unroll") for (int m = 0; m < 4; m++)                              \
    _Pragma("unroll") for (int n = 0; n < 2; n++) {                            \
      acc[(QM)*4+m][(QN)*2+n] = __builtin_amdgcn_mfma_f32_16x16x32_bf16(       \
          af[m][0], bg[n][0], acc[(QM)*4+m][(QN)*2+n], 0, 0, 0);               \
      acc[(QM)*4+m][(QN)*2+n] = __builtin_amdgcn_mfma_f32_16x16x32_bf16(       \
          af[m][1], bg[n][1], acc[(QM)*4+m][(QN)*2+n], 0, 0, 0);               \
    }                                                                          \
    __builtin_amdgcn_s_setprio(0);                                             \
    TAIL_STMT;                                                                 \
    SFENCE; __builtin_amdgcn_s_barrier(); SFENCE;                              \
  } while (0)

template <bool OUTF32>
__global__ __launch_bounds__(512, 2) void k_gemm256(const bf16_t* __restrict__ A,
                                                    const bf16_t* __restrict__ Bt,
                                                    bf16_t* __restrict__ Cb,
                                                    float* __restrict__ Cf,
                                                    int Ndim, int Kdim) {
  __shared__ bf16_t lds[4 * 16384];  // 128 KiB: A0 | B0 | A1 | B1
  const int tid = threadIdx.x;
  const int lane = tid & 63, w = tid >> 6;
  const int wm = w >> 2, wn = w & 3;
  const int l15 = lane & 15, l4 = lane >> 4;
  const int cb0 = l4 ^ (l15 & 7), cb1 = cb0 ^ 4;
  const int cswz = (tid & 7) ^ ((tid >> 3) & 7);
  const long arow0 = (long)blockIdx.y * 256;
  const long bcol0 = (long)blockIdx.x * 256;
  const bf16_t* Ab = A + arow0 * Kdim;
  const bf16_t* Bb = Bt + bcol0 * Kdim;
  const int NT = Kdim >> 6;

  bf16_t* Acur = lds;
  bf16_t* Bcur = lds + 16384;
  bf16_t* Anxt = lds + 32768;
  bf16_t* Bnxt = lds + 49152;

  f32x4 acc[8][4] = {};

  // prologue: tile0 complete + tile1 {Aq0,Bq0}; wait so tile0 landed.
  stageA(Ab, Kdim, 0, Acur, 0, tid, cswz);
  stageB(Bb, Kdim, 0, Bcur, 0, tid, cswz);
  stageA(Ab, Kdim, 0, Acur, 1, tid, cswz);
  stageB(Bb, Kdim, 0, Bcur, 1, tid, cswz);
  stageA(Ab, Kdim, 64, Anxt, 0, tid, cswz);
  stageB(Bb, Kdim, 64, Bnxt, 0, tid, cswz);
  asm volatile("s_waitcnt vmcnt(4)" ::: "memory");
  __builtin_amdgcn_s_barrier();
  SFENCE;

  for (int t = 0; t < NT; t++) {
    PHASE(0, 0, if (t + 1 < NT) stageA(Ab, Kdim, (t + 1) * 64, Anxt, 1, tid, cswz), );
    PHASE(0, 1, if (t + 1 < NT) stageB(Bb, Kdim, (t + 1) * 64, Bnxt, 1, tid, cswz), );
    PHASE(1, 0, if (t + 2 < NT) stageA(Ab, Kdim, (t + 2) * 64, Acur, 0, tid, cswz), );
    PHASE(1, 1, if (t + 2 < NT) stageB(Bb, Kdim, (t + 2) * 64, Bcur, 0, tid, cswz),
          if (t + 2 < NT) { asm volatile("s_waitcnt vmcnt(4)" ::: "memory"); }
          else            { asm volatile("s_waitcnt vmcnt(0)" ::: "memory"); });
    bf16_t* tA = Acur; Acur = Anxt; Anxt = tA;
    bf16_t* tB = Bcur; Bcur = Bnxt; Bnxt = tB;
  }

  // epilogue: C-write
#pragma unroll
  for (int i = 0; i < 8; i++) {
#pragma unroll
    for (int j = 0; j < 4; j++) {
      long row = arow0 + wm * 128 + i * 16 + l4 * 4;
      long col = bcol0 + wn * 64 + j * 16 + l15;
#pragma unroll
      for (int r = 0; r < 4; r++) {
        if constexpr (OUTF32) Cf[(row + r) * Ndim + col] = acc[i][j][r];
        else                  Cb[(row + r) * Ndim + col] = (bf16_t)acc[i][j][r];
      }
    }
  }
}

// ---------------- GEMM1 fused: A = [q|k|v] f32, converted in-kernel --------
// K = 1536 = 24 tiles of 64: tiles 0-7 read q, 8-15 k, 16-23 v (col = (t&7)*64).
// A reg-staged: pa0/pa1 hold the NEXT tile's A halves (16 f32 each); phase
// P1 writes pa0 (cvt+swizzled ds_write) then loads t+2's q0-half; P2 stages
// Bq1 (gload_lds), then writes pa1, then loads t+2's q1-half. B path and
// phase/barrier skeleton identical to k_gemm256.
DEVI const float* selsrc(int tt, const float* q, const float* k, const float* v) {
  return tt < 8 ? q : (tt < 16 ? k : v);
}

DEVI void loadAh(const float* S, long grow, int colf, float4* pa) {
  const float* p0 = S + grow * 512 + colf;
  pa[0] = *(const float4*)(p0);
  pa[1] = *(const float4*)(p0 + 4);
  const float* p1 = p0 + 128 * 512;
  pa[2] = *(const float4*)(p1);
  pa[3] = *(const float4*)(p1 + 4);
}

DEVI void writeAh(bf16_t* dst, int rbase, int cbt, const float4* pa) {
  bf16x8 o0, o1;
  o0[0] = (bf16_t)pa[0].x; o0[1] = (bf16_t)pa[0].y; o0[2] = (bf16_t)pa[0].z; o0[3] = (bf16_t)pa[0].w;
  o0[4] = (bf16_t)pa[1].x; o0[5] = (bf16_t)pa[1].y; o0[6] = (bf16_t)pa[1].z; o0[7] = (bf16_t)pa[1].w;
  o1[0] = (bf16_t)pa[2].x; o1[1] = (bf16_t)pa[2].y; o1[2] = (bf16_t)pa[2].z; o1[3] = (bf16_t)pa[2].w;
  o1[4] = (bf16_t)pa[3].x; o1[5] = (bf16_t)pa[3].y; o1[6] = (bf16_t)pa[3].z; o1[7] = (bf16_t)pa[3].w;
  int sw = (cbt ^ (rbase & 7)) * 8;
  *(bf16x8*)(dst + rbase * 64 + sw) = o0;
  *(bf16x8*)(dst + (rbase + 128) * 64 + sw) = o1;
}

#define PHASEF(QM, QN, S1, S2, S3, TAIL_STMT)                                  \
  do {                                                                         \
    bf16x8 af[4][2], bg[2][2];                                                 \
    _Pragma("unroll") for (int m = 0; m < 4; m++) {                            \
      int row = wm * 128 + (QM) * 64 + m * 16 + l15;                           \
      af[m][0] = *(const bf16x8*)(Acur + row * 64 + cb0 * 8);                  \
      af[m][1] = *(const bf16x8*)(Acur + row * 64 + cb1 * 8);                  \
    }                                                                          \
    _Pragma("unroll") for (int n = 0; n < 2; n++) {                            \
      int row = wn * 64 + (QN) * 32 + n * 16 + l15;                            \
      bg[n][0] = *(const bf16x8*)(Bcur + row * 64 + cb0 * 8);                  \
      bg[n][1] = *(const bf16x8*)(Bcur + row * 64 + cb1 * 8);                  \
    }                                                                          \
    S1;                                                                        \
    SFENCE;                                                                    \
    S2;                                                                        \
    SFENCE;                                                                    \
    S3;                                                                        \
    SFENCE; __builtin_amdgcn_s_barrier(); SFENCE;                              \
    __builtin_amdgcn_s_setprio(1);                                             \
    _Pragma("unroll") for (int m = 0; m < 4; m++)                              \
    _Pragma("unroll") for (int n = 0; n < 2; n++) {                            \
      acc[(QM)*4+m][(QN)*2+n] = __builtin_amdgcn_mfma_f32_16x16x32_bf16(       \
          af[m][0], bg[n][0], acc[(QM)*4+m][(QN)*2+n], 0, 0, 0);               \
      acc[(QM)*4+m][(QN)*2+n] = __builtin_amdgcn_mfma_f32_16x16x32_bf16(       \
          af[m][1], bg[n][1], acc[(QM)*4+m][(QN)*2+n], 0, 0, 0);               \
    }                                                                          \
    __builtin_amdgcn_s_setprio(0);                                             \
    TAIL_STMT;                                                                 \
    SFENCE; __builtin_amdgcn_s_barrier(); SFENCE;                              \
  } while (0)

__global__ __launch_bounds__(512, 2) void k_gemm1f(const float* __restrict__ q,
                                                   const float* __restrict__ k,
                                                   const float* __restrict__ v,
                                                   const bf16_t* __restrict__ Bt,
                                                   bf16_t* __restrict__ Cb,
                                                   int Ndim) {
  constexpr int Kdim = 1536;
  constexpr int NT = 24;
  __shared__ bf16_t lds[4 * 16384];  // 128 KiB: A0 | B0 | A1 | B1
  const int tid = threadIdx.x;
  const int lane = tid & 63, w = tid >> 6;
  const int wm = w >> 2, wn = w & 3;
  const int l15 = lane & 15, l4 = lane >> 4;
  const int cb0 = l4 ^ (l15 & 7), cb1 = cb0 ^ 4;
  const int cswz = (tid & 7) ^ ((tid >> 3) & 7);
  const int cbt = tid & 7, rA = tid >> 3;  // A-stage thread coords
  const long arow0 = (long)blockIdx.y * 256;
  const long bcol0 = (long)blockIdx.x * 256;
  const bf16_t* Bb = Bt + bcol0 * Kdim;

  bf16_t* Acur = lds;
  bf16_t* Bcur = lds + 16384;
  bf16_t* Anxt = lds + 32768;
  bf16_t* Bnxt = lds + 49152;

  f32x4 acc[8][4] = {};
  float4 pa0[4], pa1[4];

  // ---- prologue ----
  // tile0 A -> regs -> LDS buffer0 (compiler inserts the load->write vmcnt)
  loadAh(selsrc(0, q, k, v), arow0 + rA,      (cbt << 3), pa0);
  loadAh(selsrc(0, q, k, v), arow0 + rA + 64, (cbt << 3), pa1);
  SFENCE;
  writeAh(Acur, rA,      cbt, pa0);
  writeAh(Acur, rA + 64, cbt, pa1);
  SFENCE;
  stageB(Bb, Kdim, 0, Bcur, 0, tid, cswz);   // Bq0(0)
  stageB(Bb, Kdim, 0, Bcur, 1, tid, cswz);   // Bq1(0)
  SFENCE;
  loadAh(selsrc(1, q, k, v), arow0 + rA,      64 + (cbt << 3), pa0);  // A0(1)
  loadAh(selsrc(1, q, k, v), arow0 + rA + 64, 64 + (cbt << 3), pa1);  // A1(1)
  SFENCE;
  stageB(Bb, Kdim, 64, Bnxt, 0, tid, cswz);  // Bq0(1)
  SFENCE;
  // newer-than-Bq1(0) = pa(1) loads (8) + Bq0(1) (2) = 10
  asm volatile("s_waitcnt vmcnt(10)" ::: "memory");
  asm volatile("s_waitcnt lgkmcnt(0)" ::: "memory");
  __builtin_amdgcn_s_barrier();
  SFENCE;

  for (int t = 0; t < NT; t++) {
    // P1: write A0(t+1) -> Anxt, then load A0(t+2) into pa0
    PHASEF(0, 0,
           if (t + 1 < NT) writeAh(Anxt, rA, cbt, pa0),
           if (t + 2 < NT) loadAh(selsrc(t + 2, q, k, v), arow0 + rA,
                                  (((t + 2) & 7) << 6) + (cbt << 3), pa0),
           , );
    // P2: stage Bq1(t+1); write A1(t+1); load A1(t+2)
    PHASEF(0, 1,
           if (t + 1 < NT) stageB(Bb, Kdim, (t + 1) * 64, Bnxt, 1, tid, cswz),
           if (t + 1 < NT) writeAh(Anxt, rA + 64, cbt, pa1),
           if (t + 2 < NT) loadAh(selsrc(t + 2, q, k, v), arow0 + rA + 64,
                                  (((t + 2) & 7) << 6) + (cbt << 3), pa1),
           );
    // P3: plain compute
    PHASEF(1, 0, , , , );
    // P4: stage Bq0(t+2) -> Bcur; boundary counted wait
    PHASEF(1, 1,
           if (t + 2 < NT) stageB(Bb, Kdim, (t + 2) * 64, Bcur, 0, tid, cswz),
           , ,
           if (t + 2 < NT) { asm volatile("s_waitcnt vmcnt(6)" ::: "memory"); }
           else            { asm volatile("s_waitcnt vmcnt(0)" ::: "memory"); });
    bf16_t* tA = Acur; Acur = Anxt; Anxt = tA;
    bf16_t* tB = Bcur; Bcur = Bnxt; Bnxt = tB;
  }

  // epilogue: C-write (bf16)
#pragma unroll
  for (int i = 0; i < 8; i++) {
#pragma unroll
    for (int j = 0; j < 4; j++) {
      long row = arow0 + wm * 128 + i * 16 + l4 * 4;
      long col = bcol0 + wn * 64 + j * 16 + l15;
#pragma unroll
      for (int r = 0; r < 4; r++)
        Cb[(row + r) * Ndim + col] = (bf16_t)acc[i][j][r];
    }
  }
}

// ---------------- attention: one WG per (b, seg, head) ---------------------
__global__ __launch_bounds__(256, 2) void k_attn(const bf16_t* __restrict__ QKV,
                                                 const int* __restrict__ perm,
                                                 bf16_t* __restrict__ ATT) {
  __shared__ bf16_t Vt[2][64 * 64];
  __shared__ bf16_t P[2][64 * 64];
  __shared__ bf16_t O[128 * 64];
  __shared__ int perml[128];
  const int n = blockIdx.x, h = blockIdx.y, b = blockIdx.z;
  const int t = threadIdx.x;
  const int lane = t & 63, w = t >> 6;
  const int l15 = lane & 15, l4 = lane >> 4;

  if (t < 128) perml[t] = perm[n * 128 + t];
  __syncthreads();

  // ---- gather V, transposed: Vt[grp][d][s] (row=d 128B, XOR-swizzled) ----
#pragma unroll
  for (int it = 0; it < 4; it++) {
    int c = t + it * 256;           // 0..1023
    int tok = c >> 3, c8 = c & 7;   // token-local, 8-elem chunk of d
    long j = (long)b * Mtok + perml[tok];
    bf16x8 vv = *(const bf16x8*)(QKV + j * 1536 + 1024 + h * 64 + c8 * 8);
    int grp = tok & 1, s = tok >> 1;
    bf16_t* vt = Vt[grp];
#pragma unroll
    for (int i = 0; i < 8; i++) {
      int d = c8 * 8 + i;
      vt[d * 64 + (s ^ ((d & 7) << 3))] = vv[i];
    }
  }

  const int grp = w >> 1, th = w & 1;

  // ---- QK^T : scores[t][s], fragments direct from global ----
  f32x4 sc[2][4] = {};
#pragma unroll
  for (int ks = 0; ks < 2; ks++) {
    bf16x8 aq[2], bk[4];
#pragma unroll
    for (int tf = 0; tf < 2; tf++) {
      int tq = th * 32 + tf * 16 + l15;
      long j = (long)b * Mtok + perml[tq * 2 + grp];
      aq[tf] = *(const bf16x8*)(QKV + j * 1536 + h * 64 + ks * 32 + l4 * 8);
    }
#pragma unroll
    for (int sf = 0; sf < 4; sf++) {
      int s = sf * 16 + l15;
      long j = (long)b * Mtok + perml[s * 2 + grp];
      bk[sf] = *(const bf16x8*)(QKV + j * 1536 + 512 + h * 64 + ks * 32 + l4 * 8);
    }
#pragma unroll
    for (int tf = 0; tf < 2; tf++)
#pragma unroll
      for (int sf = 0; sf < 4; sf++)
        sc[tf][sf] = __builtin_amdgcn_mfma_f32_16x16x32_bf16(aq[tf], bk[sf], sc[tf][sf], 0, 0, 0);
  }

  // ---- softmax over s (64), wave-parallel 16-lane reductions ----
  const float scale = 0.125f;  // 1/sqrt(64)
#pragma unroll
  for (int tf = 0; tf < 2; tf++) {
#pragma unroll
    for (int r = 0; r < 4; r++) {
      float mx = fmaxf(fmaxf(sc[tf][0][r], sc[tf][1][r]), fmaxf(sc[tf][2][r], sc[tf][3][r]));
      mx = fmaxf(mx, __shfl_xor(mx, 1, 64));
      mx = fmaxf(mx, __shfl_xor(mx, 2, 64));
      mx = fmaxf(mx, __shfl_xor(mx, 4, 64));
      mx = fmaxf(mx, __shfl_xor(mx, 8, 64));
      float p0 = __expf((sc[tf][0][r] - mx) * scale);
      float p1 = __expf((sc[tf][1][r] - mx) * scale);
      float p2 = __expf((sc[tf][2][r] - mx) * scale);
      float p3 = __expf((sc[tf][3][r] - mx) * scale);
      float sum = p0 + p1 + p2 + p3;
      sum += __shfl_xor(sum, 1, 64);
      sum += __shfl_xor(sum, 2, 64);
      sum += __shfl_xor(sum, 4, 64);
      sum += __shfl_xor(sum, 8, 64);
      float inv = 1.0f / sum;
      int trow = th * 32 + tf * 16 + l4 * 4 + r;
      int sw = (trow & 7) << 3;
      bf16_t* pp = P[grp];
      pp[trow * 64 + ((l15     ) ^ sw)] = (bf16_t)(p0 * inv);
      pp[trow * 64 + ((l15 + 16) ^ sw)] = (bf16_t)(p1 * inv);
      pp[trow * 64 + ((l15 + 32) ^ sw)] = (bf16_t)(p2 * inv);
      pp[trow * 64 + ((l15 + 48) ^ sw)] = (bf16_t)(p3 * inv);
    }
  }
  __syncthreads();  // P + Vt visible to all

  // ---- PV : out[t][d] ----
  f32x4 oacc[2][4] = {};
#pragma unroll
  for (int ks = 0; ks < 2; ks++) {
    bf16x8 ap[2], bv[4];
#pragma unroll
    for (int tf = 0; tf < 2; tf++) {
      int trow = th * 32 + tf * 16 + l15;
      int cb = (ks * 4 + l4) ^ (trow & 7);
      ap[tf] = *(const bf16x8*)(P[grp] + trow * 64 + cb * 8);
    }
#pragma unroll
    for (int df = 0; df < 4; df++) {
      int d = df * 16 + l15;
      int cb = (ks * 4 + l4) ^ (d & 7);
      bv[df] = *(const bf16x8*)(Vt[grp] + d * 64 + cb * 8);
    }
#pragma unroll
    for (int tf = 0; tf < 2; tf++)
#pragma unroll
      for (int df = 0; df < 4; df++)
        oacc[tf][df] = __builtin_amdgcn_mfma_f32_16x16x32_bf16(ap[tf], bv[df], oacc[tf][df], 0, 0, 0);
  }

  // ---- stage output rows in LDS, then coalesced scatter (128B chunks) ----
#pragma unroll
  for (int tf = 0; tf < 2; tf++)
#pragma unroll
    for (int df = 0; df < 4; df++)
#pragma unroll
      for (int r = 0; r < 4; r++) {
        int trow = th * 32 + tf * 16 + l4 * 4 + r;
        int tok = trow * 2 + grp;   // position within segment (PERM order)
        O[tok * 64 + df * 16 + l15] = (bf16_t)oacc[tf][df][r];
      }
  __syncthreads();
#pragma unroll
  for (int it = 0; it < 4; it++) {
    int c = t + it * 256;
    int tok = c >> 3, c8 = c & 7;
    long j = (long)b * Mtok + perml[tok];  // inverse-permute == scatter to PERM[i]
    *(bf16x8*)(ATT + j * 512 + h * 64 + c8 * 8) = *(const bf16x8*)(O + tok * 64 + c8 * 8);
  }
}

// ---------------------------------------------------------------------------
extern "C" void kernel_launch(void* const* d_in, const int* in_sizes, int n_in,
                              void* d_out, int out_size, void* d_ws, size_t ws_size,
                              hipStream_t stream) {
  const float* q    = (const float*)d_in[0];
  const float* k    = (const float*)d_in[1];
  const float* v    = (const float*)d_in[2];
  const float* Wq   = (const float*)d_in[3];
  const float* Wk   = (const float*)d_in[4];
  const float* Wv   = (const float*)d_in[5];
  const float* Wqkv = (const float*)d_in[6];
  const float* Wout = (const float*)d_in[7];

  char* ws = (char*)d_ws;
  const size_t QKV_BYTES = (size_t)ROWS * 1536 * 2;  // 100,663,296
  const size_t X_BYTES   = (size_t)ROWS * 512 * 2;   //  33,554,432
  bf16_t* QKV   = (bf16_t*)ws;
  bf16_t* X     = (bf16_t*)(ws + QKV_BYTES);          // also ATT (X dead after GEMM2)
  bf16_t* W1t   = (bf16_t*)(ws + QKV_BYTES + X_BYTES);
  bf16_t* Wqkvt = W1t + 512 * 1536;
  bf16_t* Woutt = Wqkvt + 1536 * 512;
  int*    perm  = (int*)(Woutt + 512 * 512);

  k_perm<<<64, 256, 0, stream>>>(perm);
  k_prep_w<<<512, 256, 0, stream>>>(Wq, Wk, Wv, Wqkv, Wout, W1t, Wqkvt, Woutt);
  // GEMM1 (fused f32->bf16): X = [q|k|v] @ W1 (M=32768, N=512, K=1536)
  k_gemm1f<<<dim3(2, 128), 512, 0, stream>>>(q, k, v, W1t, X, 512);
  // GEMM2: QKV = X @ Wqkv (N=1536, K=512)
  k_gemm256<false><<<dim3(6, 128), 512, 0, stream>>>(X, Wqkvt, QKV, nullptr, 1536, 512);
  // attention: reads QKV, writes ATT (aliases X)
  k_attn<<<dim3(128, 8, 2), 256, 0, stream>>>(QKV, perm, X);
  // GEMM3: out = ATT @ Wout (f32 output)
  k_gemm256<true><<<dim3(2, 128), 512, 0, stream>>>(X, Woutt, nullptr, (float*)d_out, 512, 512);
}

// Round 4
// 229.159 us; speedup vs baseline: 1.2160x; 1.0207x over previous
//
#include <hip/hip_runtime.h>
#include <hip/hip_bf16.h>
#include <stdint.h>

// ---------------------------------------------------------------------------
// HilbertAttention pipeline, bf16 MFMA implementation.
//   x   = ([q|k|v] @ W1t^T)/3        (GEMM1 fused f32->bf16 A-staging)
//   qkv = x @ Wqkvt^T                (GEMM2)
//   attention (Hilbert, 128-seg, dil 2 -> 4096 groups of 64x64)
//   out = att @ Woutt^T  (f32 out)   (GEMM3)
// GEMMs: 256x256 tile, BK=64, 8 waves (2Mx4N), ring-2 LDS double-buffer,
// Z-ordered 4-phase (q0n0,q0n1,q1n1,q1n0) with cross-phase fragment reg-reuse
// (28 ds_read_b128/tile/wave instead of 48), counted vmcnt (T4), setprio (T5),
// XOR-swizzled LDS (T2).
// Stage slots (re-derived for Z-order; last reads: Aq0@P2, Bn1@P3, Bn0/Aq1@P4):
//   P1: Bn0(t+1)->nxt   P2: Aq1(t+1)->nxt   P3: Aq0(t+2)->cur   P4: Bn1(t+2)->cur
// ---------------------------------------------------------------------------

typedef __bf16 bf16_t;
typedef __bf16 bf16x8 __attribute__((ext_vector_type(8)));
typedef float  f32x4  __attribute__((ext_vector_type(4)));

#define DEVI __device__ __forceinline__
#define SFENCE __builtin_amdgcn_sched_barrier(0)
#define PH_BAR do { SFENCE; __builtin_amdgcn_s_barrier(); SFENCE; } while (0)

static constexpr int Mtok = 16384;   // tokens per batch
static constexpr int ROWS = 32768;   // B * Mtok

DEVI void gload_lds16(const void* g, void* l) {
  __builtin_amdgcn_global_load_lds(
      (__attribute__((address_space(1))) uint32_t*)(uintptr_t)g,
      (__attribute__((address_space(3))) uint32_t*)(uint32_t)(uintptr_t)l,
      16, 0, 0);
}

// ---------------- Hilbert permutation (n = 128 grid) -----------------------
__global__ void k_perm(int* __restrict__ perm) {
  int d = blockIdx.x * 256 + threadIdx.x;
  if (d >= Mtok) return;
  int t = d, x = 0, y = 0;
  for (int s = 1; s < 128; s <<= 1) {
    int rx = (t >> 1) & 1;
    int ry = (t ^ rx) & 1;
    if (ry == 0) {
      if (rx == 1) { x = s - 1 - x; y = s - 1 - y; }
      int tmp = x; x = y; y = tmp;
    }
    x += s * rx;
    y += s * ry;
    t >>= 2;
  }
  perm[d] = y * 128 + x;
}

// ---------------- transpose weights to bf16 B^T row-major ------------------
__global__ void k_prep_w(const float* __restrict__ Wq, const float* __restrict__ Wk,
                         const float* __restrict__ Wv, const float* __restrict__ Wqkv,
                         const float* __restrict__ Wout,
                         bf16_t* __restrict__ W1t, bf16_t* __restrict__ Wqkvt,
                         bf16_t* __restrict__ Woutt) {
  const int tid = blockIdx.x * 256 + threadIdx.x;
  const int stride = gridDim.x * 256;
  for (int i = tid; i < 512 * 1536; i += stride) {
    int n = i / 1536, kk = i % 1536;
    const float* W = (kk < 512) ? Wq : (kk < 1024 ? Wk : Wv);
    W1t[i] = (bf16_t)(W[(kk & 511) * 512 + n] * (1.0f / 3.0f));
  }
  for (int i = tid; i < 1536 * 512; i += stride) {
    int n = i / 512, kk = i % 512;
    Wqkvt[i] = (bf16_t)Wqkv[kk * 1536 + n];
  }
  for (int i = tid; i < 512 * 512; i += stride) {
    int n = i / 512, kk = i % 512;
    Woutt[i] = (bf16_t)Wout[kk * 512 + n];
  }
}

// ---------------- staging helpers ------------------------------------------
DEVI void stageB(const bf16_t* Bb, int Kdim, int k0, bf16_t* dst, int qsel,
                 int tid, int cswz) {
  int r = tid >> 3;
  int rb0 = (r >> 5) * 64 + qsel * 32 + (r & 31);
  const bf16_t* g = Bb + (long)rb0 * Kdim + k0 + cswz * 8;
  gload_lds16(g, dst + rb0 * 64 + (tid & 7) * 8);
  gload_lds16(g + (long)128 * Kdim, dst + (rb0 + 128) * 64 + (tid & 7) * 8);
}

DEVI void stageA(const bf16_t* Ab, int Kdim, int k0, bf16_t* dst, int qsel,
                 int tid, int cswz) {
  int r = tid >> 3;
  int row0 = r + qsel * 64;
  const bf16_t* g = Ab + (long)row0 * Kdim + k0 + cswz * 8;
  gload_lds16(g, dst + row0 * 64 + (tid & 7) * 8);
  gload_lds16(g + (long)128 * Kdim, dst + (row0 + 128) * 64 + (tid & 7) * 8);
}

// ---------------- fragment load / MFMA helpers ------------------------------
#define LOAD_AF(AF, QM, BUF)                                                   \
  _Pragma("unroll") for (int m = 0; m < 4; m++) {                              \
    int row = wm * 128 + (QM) * 64 + m * 16 + l15;                             \
    AF[m][0] = *(const bf16x8*)((BUF) + row * 64 + cb0 * 8);                   \
    AF[m][1] = *(const bf16x8*)((BUF) + row * 64 + cb1 * 8);                   \
  }
#define LOAD_BG(BG, QN, BUF)                                                   \
  _Pragma("unroll") for (int n = 0; n < 2; n++) {                              \
    int row = wn * 64 + (QN) * 32 + n * 16 + l15;                              \
    BG[n][0] = *(const bf16x8*)((BUF) + row * 64 + cb0 * 8);                   \
    BG[n][1] = *(const bf16x8*)((BUF) + row * 64 + cb1 * 8);                   \
  }
#define QUAD(QM, QN, AF, BG)                                                   \
  do {                                                                         \
    __builtin_amdgcn_s_setprio(1);                                             \
    _Pragma("unroll") for (int kh = 0; kh < 2; kh++)                           \
    _Pragma("unroll") for (int m = 0; m < 4; m++)                              \
    _Pragma("unroll") for (int n = 0; n < 2; n++)                              \
      acc[(QM)*4+m][(QN)*2+n] = __builtin_amdgcn_mfma_f32_16x16x32_bf16(       \
          AF[m][kh], BG[n][kh], acc[(QM)*4+m][(QN)*2+n], 0, 0, 0);             \
    __builtin_amdgcn_s_setprio(0);                                             \
  } while (0)

// ---------------- generic 256x256 GEMM (bf16 A in memory) ------------------
template <bool OUTF32>
__global__ __launch_bounds__(512, 2) void k_gemm256(const bf16_t* __restrict__ A,
                                                    const bf16_t* __restrict__ Bt,
                                                    bf16_t* __restrict__ Cb,
                                                    float* __restrict__ Cf,
                                                    int Ndim, int Kdim) {
  __shared__ bf16_t lds[4 * 16384];  // 128 KiB: A0 | B0 | A1 | B1
  const int tid = threadIdx.x;
  const int lane = tid & 63, w = tid >> 6;
  const int wm = w >> 2, wn = w & 3;
  const int l15 = lane & 15, l4 = lane >> 4;
  const int cb0 = l4 ^ (l15 & 7), cb1 = cb0 ^ 4;
  const int cswz = (tid & 7) ^ ((tid >> 3) & 7);
  const long arow0 = (long)blockIdx.y * 256;
  const long bcol0 = (long)blockIdx.x * 256;
  const bf16_t* Ab = A + arow0 * Kdim;
  const bf16_t* Bb = Bt + bcol0 * Kdim;
  const int NT = Kdim >> 6;

  bf16_t* Acur = lds;
  bf16_t* Bcur = lds + 16384;
  bf16_t* Anxt = lds + 32768;
  bf16_t* Bnxt = lds + 49152;

  f32x4 acc[8][4] = {};

  // prologue: tile0 complete -> cur; tile1 {Aq0, Bn1} -> nxt.
  stageA(Ab, Kdim, 0, Acur, 0, tid, cswz);
  stageA(Ab, Kdim, 0, Acur, 1, tid, cswz);
  stageB(Bb, Kdim, 0, Bcur, 0, tid, cswz);
  stageB(Bb, Kdim, 0, Bcur, 1, tid, cswz);
  stageA(Ab, Kdim, 64, Anxt, 0, tid, cswz);
  stageB(Bb, Kdim, 64, Bnxt, 1, tid, cswz);
  asm volatile("s_waitcnt vmcnt(4)" ::: "memory");  // tile0 landed
  __builtin_amdgcn_s_barrier();
  SFENCE;

  for (int t = 0; t < NT; t++) {
    bf16x8 af[4][2], bg0[2][2], bg1[2][2];
    // P1 (q0,n0): stage Bn0(t+1)->nxt
    LOAD_AF(af, 0, Acur);
    LOAD_BG(bg0, 0, Bcur);
    if (t + 1 < NT) stageB(Bb, Kdim, (t + 1) * 64, Bnxt, 0, tid, cswz);
    PH_BAR;
    QUAD(0, 0, af, bg0);
    PH_BAR;
    // P2 (q0,n1): stage Aq1(t+1)->nxt   (af reused)
    LOAD_BG(bg1, 1, Bcur);
    if (t + 1 < NT) stageA(Ab, Kdim, (t + 1) * 64, Anxt, 1, tid, cswz);
    PH_BAR;
    QUAD(0, 1, af, bg1);
    PH_BAR;
    // P3 (q1,n1): stage Aq0(t+2)->cur   (bg1 reused; Aq0 last read P2)
    LOAD_AF(af, 1, Acur);
    if (t + 2 < NT) stageA(Ab, Kdim, (t + 2) * 64, Acur, 0, tid, cswz);
    PH_BAR;
    QUAD(1, 1, af, bg1);
    PH_BAR;
    // P4 (q1,n0): stage Bn1(t+2)->cur   (af reused; bg0 reloaded; Bn1 last read P3)
    LOAD_BG(bg0, 0, Bcur);
    if (t + 2 < NT) stageB(Bb, Kdim, (t + 2) * 64, Bcur, 1, tid, cswz);
    PH_BAR;
    QUAD(1, 0, af, bg0);
    if (t + 2 < NT) { asm volatile("s_waitcnt vmcnt(4)" ::: "memory"); }
    else            { asm volatile("s_waitcnt vmcnt(0)" ::: "memory"); }
    PH_BAR;
    bf16_t* tA = Acur; Acur = Anxt; Anxt = tA;
    bf16_t* tB = Bcur; Bcur = Bnxt; Bnxt = tB;
  }

  // epilogue: C-write
#pragma unroll
  for (int i = 0; i < 8; i++) {
#pragma unroll
    for (int j = 0; j < 4; j++) {
      long row = arow0 + wm * 128 + i * 16 + l4 * 4;
      long col = bcol0 + wn * 64 + j * 16 + l15;
#pragma unroll
      for (int r = 0; r < 4; r++) {
        if constexpr (OUTF32) Cf[(row + r) * Ndim + col] = acc[i][j][r];
        else                  Cb[(row + r) * Ndim + col] = (bf16_t)acc[i][j][r];
      }
    }
  }
}

// ---------------- GEMM1 fused: A = [q|k|v] f32, converted in-kernel --------
// K = 1536 = 24 tiles of 64: tiles 0-7 q, 8-15 k, 16-23 v (col = (t&7)*64).
// A halves: q0 = rows {0-63,128-191}, q1 = rows {64-127,192-255}.
// pa1 holds Aq1(t+2) (written P2 of t+1); pa0 holds Aq0(t+3) (written P3 of t+2).
DEVI const float* selsrc(int tt, const float* q, const float* k, const float* v) {
  return tt < 8 ? q : (tt < 16 ? k : v);
}

DEVI void loadAh(const float* S, long grow, int colf, float4* pa) {
  const float* p0 = S + grow * 512 + colf;
  pa[0] = *(const float4*)(p0);
  pa[1] = *(const float4*)(p0 + 4);
  const float* p1 = p0 + 128 * 512;
  pa[2] = *(const float4*)(p1);
  pa[3] = *(const float4*)(p1 + 4);
}

DEVI void writeAh(bf16_t* dst, int rbase, int cbt, const float4* pa) {
  bf16x8 o0, o1;
  o0[0] = (bf16_t)pa[0].x; o0[1] = (bf16_t)pa[0].y; o0[2] = (bf16_t)pa[0].z; o0[3] = (bf16_t)pa[0].w;
  o0[4] = (bf16_t)pa[1].x; o0[5] = (bf16_t)pa[1].y; o0[6] = (bf16_t)pa[1].z; o0[7] = (bf16_t)pa[1].w;
  o1[0] = (bf16_t)pa[2].x; o1[1] = (bf16_t)pa[2].y; o1[2] = (bf16_t)pa[2].z; o1[3] = (bf16_t)pa[2].w;
  o1[4] = (bf16_t)pa[3].x; o1[5] = (bf16_t)pa[3].y; o1[6] = (bf16_t)pa[3].z; o1[7] = (bf16_t)pa[3].w;
  int sw = (cbt ^ (rbase & 7)) * 8;
  *(bf16x8*)(dst + rbase * 64 + sw) = o0;
  *(bf16x8*)(dst + (rbase + 128) * 64 + sw) = o1;
}

__global__ __launch_bounds__(512, 2) void k_gemm1f(const float* __restrict__ q,
                                                   const float* __restrict__ k,
                                                   const float* __restrict__ v,
                                                   const bf16_t* __restrict__ Bt,
                                                   bf16_t* __restrict__ Cb,
                                                   int Ndim) {
  constexpr int Kdim = 1536;
  constexpr int NT = 24;
  __shared__ bf16_t lds[4 * 16384];  // 128 KiB
  const int tid = threadIdx.x;
  const int lane = tid & 63, w = tid >> 6;
  const int wm = w >> 2, wn = w & 3;
  const int l15 = lane & 15, l4 = lane >> 4;
  const int cb0 = l4 ^ (l15 & 7), cb1 = cb0 ^ 4;
  const int cswz = (tid & 7) ^ ((tid >> 3) & 7);
  const int cbt = tid & 7, rA = tid >> 3;
  const long arow0 = (long)blockIdx.y * 256;
  const long bcol0 = (long)blockIdx.x * 256;
  const bf16_t* Bb = Bt + bcol0 * Kdim;

  bf16_t* Acur = lds;
  bf16_t* Bcur = lds + 16384;
  bf16_t* Anxt = lds + 32768;
  bf16_t* Bnxt = lds + 49152;

  f32x4 acc[8][4] = {};
  float4 pa0[4], pa1[4];

  // ---- prologue ----
  // tile0 A -> cur (via regs; compiler inserts the load->write waits)
  loadAh(selsrc(0, q, k, v), arow0 + rA,      (cbt << 3), pa0);
  loadAh(selsrc(0, q, k, v), arow0 + rA + 64, (cbt << 3), pa1);
  SFENCE;
  writeAh(Acur, rA,      cbt, pa0);
  writeAh(Acur, rA + 64, cbt, pa1);
  SFENCE;
  stageB(Bb, Kdim, 0, Bcur, 0, tid, cswz);   // Bn0(0)
  stageB(Bb, Kdim, 0, Bcur, 1, tid, cswz);   // Bn1(0)
  SFENCE;
  loadAh(selsrc(1, q, k, v), arow0 + rA, 64 + (cbt << 3), pa0);  // Aq0(1)
  SFENCE;
  writeAh(Anxt, rA, cbt, pa0);                                    // -> nxt
  SFENCE;
  stageB(Bb, Kdim, 64, Bnxt, 1, tid, cswz);  // Bn1(1) -> nxt
  SFENCE;
  loadAh(selsrc(1, q, k, v), arow0 + rA + 64,  64 + (cbt << 3), pa1);  // Aq1(1)
  loadAh(selsrc(2, q, k, v), arow0 + rA,      128 + (cbt << 3), pa0);  // Aq0(2)
  SFENCE;
  // outstanding: Bn0(0)x2, Bn1(0)x2, Bn1(1)x2, pa1 x8, pa0 x8 = 22; retire tile0 B.
  asm volatile("s_waitcnt vmcnt(18)" ::: "memory");
  asm volatile("s_waitcnt lgkmcnt(0)" ::: "memory");
  __builtin_amdgcn_s_barrier();
  SFENCE;

  for (int t = 0; t < NT; t++) {
    bf16x8 af[4][2], bg0[2][2], bg1[2][2];
    // P1 (q0,n0): stage Bn0(t+1)->nxt
    LOAD_AF(af, 0, Acur);
    LOAD_BG(bg0, 0, Bcur);
    if (t + 1 < NT) stageB(Bb, Kdim, (t + 1) * 64, Bnxt, 0, tid, cswz);
    PH_BAR;
    QUAD(0, 0, af, bg0);
    PH_BAR;
    // P2 (q0,n1): write Aq1(t+1)->nxt, then load pa1 <- Aq1(t+2)
    LOAD_BG(bg1, 1, Bcur);
    if (t + 1 < NT) writeAh(Anxt, rA + 64, cbt, pa1);
    SFENCE;
    if (t + 2 < NT) loadAh(selsrc(t + 2, q, k, v), arow0 + rA + 64,
                           (((t + 2) & 7) << 6) + (cbt << 3), pa1);
    PH_BAR;
    QUAD(0, 1, af, bg1);
    PH_BAR;
    // P3 (q1,n1): write Aq0(t+2)->cur (Aq0 last read P2), load pa0 <- Aq0(t+3)
    LOAD_AF(af, 1, Acur);
    if (t + 2 < NT) writeAh(Acur, rA, cbt, pa0);
    SFENCE;
    if (t + 3 < NT) loadAh(selsrc(t + 3, q, k, v), arow0 + rA,
                           (((t + 3) & 7) << 6) + (cbt << 3), pa0);
    PH_BAR;
    QUAD(1, 1, af, bg1);
    PH_BAR;
    // P4 (q1,n0): stage Bn1(t+2)->cur (Bn1 last read P3); bg0 reloaded
    LOAD_BG(bg0, 0, Bcur);
    if (t + 2 < NT) stageB(Bb, Kdim, (t + 2) * 64, Bcur, 1, tid, cswz);
    PH_BAR;
    QUAD(1, 0, af, bg0);
    // boundary: retire Bn0(t+1) (oldest); keep pa/B prefetches in flight.
    if (t + 3 < NT)      { asm volatile("s_waitcnt vmcnt(18)" ::: "memory"); }
    else if (t + 2 < NT) { asm volatile("s_waitcnt vmcnt(10)" ::: "memory"); }
    else                 { asm volatile("s_waitcnt vmcnt(0)"  ::: "memory"); }
    asm volatile("s_waitcnt lgkmcnt(0)" ::: "memory");
    PH_BAR;
    bf16_t* tA = Acur; Acur = Anxt; Anxt = tA;
    bf16_t* tB = Bcur; Bcur = Bnxt; Bnxt = tB;
  }

  // epilogue: C-write (bf16)
#pragma unroll
  for (int i = 0; i < 8; i++) {
#pragma unroll
    for (int j = 0; j < 4; j++) {
      long row = arow0 + wm * 128 + i * 16 + l4 * 4;
      long col = bcol0 + wn * 64 + j * 16 + l15;
#pragma unroll
      for (int r = 0; r < 4; r++)
        Cb[(row + r) * Ndim + col] = (bf16_t)acc[i][j][r];
    }
  }
}

// ---------------- attention: one WG per (b, seg, head) ---------------------
__global__ __launch_bounds__(256, 2) void k_attn(const bf16_t* __restrict__ QKV,
                                                 const int* __restrict__ perm,
                                                 bf16_t* __restrict__ ATT) {
  __shared__ bf16_t Vt[2][64 * 64];
  __shared__ bf16_t P[2][64 * 64];
  __shared__ bf16_t O[128 * 64];
  __shared__ int perml[128];
  const int n = blockIdx.x, h = blockIdx.y, b = blockIdx.z;
  const int t = threadIdx.x;
  const int lane = t & 63, w = t >> 6;
  const int l15 = lane & 15, l4 = lane >> 4;

  if (t < 128) perml[t] = perm[n * 128 + t];
  __syncthreads();

  // ---- gather V, transposed: Vt[grp][d][s] (row=d 128B, XOR-swizzled) ----
#pragma unroll
  for (int it = 0; it < 4; it++) {
    int c = t + it * 256;           // 0..1023
    int tok = c >> 3, c8 = c & 7;   // token-local, 8-elem chunk of d
    long j = (long)b * Mtok + perml[tok];
    bf16x8 vv = *(const bf16x8*)(QKV + j * 1536 + 1024 + h * 64 + c8 * 8);
    int grp = tok & 1, s = tok >> 1;
    bf16_t* vt = Vt[grp];
#pragma unroll
    for (int i = 0; i < 8; i++) {
      int d = c8 * 8 + i;
      vt[d * 64 + (s ^ ((d & 7) << 3))] = vv[i];
    }
  }

  const int grp = w >> 1, th = w & 1;

  // ---- QK^T : scores[t][s], fragments direct from global ----
  f32x4 sc[2][4] = {};
#pragma unroll
  for (int ks = 0; ks < 2; ks++) {
    bf16x8 aq[2], bk[4];
#pragma unroll
    for (int tf = 0; tf < 2; tf++) {
      int tq = th * 32 + tf * 16 + l15;
      long j = (long)b * Mtok + perml[tq * 2 + grp];
      aq[tf] = *(const bf16x8*)(QKV + j * 1536 + h * 64 + ks * 32 + l4 * 8);
    }
#pragma unroll
    for (int sf = 0; sf < 4; sf++) {
      int s = sf * 16 + l15;
      long j = (long)b * Mtok + perml[s * 2 + grp];
      bk[sf] = *(const bf16x8*)(QKV + j * 1536 + 512 + h * 64 + ks * 32 + l4 * 8);
    }
#pragma unroll
    for (int tf = 0; tf < 2; tf++)
#pragma unroll
      for (int sf = 0; sf < 4; sf++)
        sc[tf][sf] = __builtin_amdgcn_mfma_f32_16x16x32_bf16(aq[tf], bk[sf], sc[tf][sf], 0, 0, 0);
  }

  // ---- softmax over s (64), wave-parallel 16-lane reductions ----
  const float scale = 0.125f;  // 1/sqrt(64)
#pragma unroll
  for (int tf = 0; tf < 2; tf++) {
#pragma unroll
    for (int r = 0; r < 4; r++) {
      float mx = fmaxf(fmaxf(sc[tf][0][r], sc[tf][1][r]), fmaxf(sc[tf][2][r], sc[tf][3][r]));
      mx = fmaxf(mx, __shfl_xor(mx, 1, 64));
      mx = fmaxf(mx, __shfl_xor(mx, 2, 64));
      mx = fmaxf(mx, __shfl_xor(mx, 4, 64));
      mx = fmaxf(mx, __shfl_xor(mx, 8, 64));
      float p0 = __expf((sc[tf][0][r] - mx) * scale);
      float p1 = __expf((sc[tf][1][r] - mx) * scale);
      float p2 = __expf((sc[tf][2][r] - mx) * scale);
      float p3 = __expf((sc[tf][3][r] - mx) * scale);
      float sum = p0 + p1 + p2 + p3;
      sum += __shfl_xor(sum, 1, 64);
      sum += __shfl_xor(sum, 2, 64);
      sum += __shfl_xor(sum, 4, 64);
      sum += __shfl_xor(sum, 8, 64);
      float inv = 1.0f / sum;
      int trow = th * 32 + tf * 16 + l4 * 4 + r;
      int sw = (trow & 7) << 3;
      bf16_t* pp = P[grp];
      pp[trow * 64 + ((l15     ) ^ sw)] = (bf16_t)(p0 * inv);
      pp[trow * 64 + ((l15 + 16) ^ sw)] = (bf16_t)(p1 * inv);
      pp[trow * 64 + ((l15 + 32) ^ sw)] = (bf16_t)(p2 * inv);
      pp[trow * 64 + ((l15 + 48) ^ sw)] = (bf16_t)(p3 * inv);
    }
  }
  __syncthreads();  // P + Vt visible to all

  // ---- PV : out[t][d] ----
  f32x4 oacc[2][4] = {};
#pragma unroll
  for (int ks = 0; ks < 2; ks++) {
    bf16x8 ap[2], bv[4];
#pragma unroll
    for (int tf = 0; tf < 2; tf++) {
      int trow = th * 32 + tf * 16 + l15;
      int cb = (ks * 4 + l4) ^ (trow & 7);
      ap[tf] = *(const bf16x8*)(P[grp] + trow * 64 + cb * 8);
    }
#pragma unroll
    for (int df = 0; df < 4; df++) {
      int d = df * 16 + l15;
      int cb = (ks * 4 + l4) ^ (d & 7);
      bv[df] = *(const bf16x8*)(Vt[grp] + d * 64 + cb * 8);
    }
#pragma unroll
    for (int tf = 0; tf < 2; tf++)
#pragma unroll
      for (int df = 0; df < 4; df++)
        oacc[tf][df] = __builtin_amdgcn_mfma_f32_16x16x32_bf16(ap[tf], bv[df], oacc[tf][df], 0, 0, 0);
  }

  // ---- stage output rows in LDS, then coalesced scatter (128B chunks) ----
#pragma unroll
  for (int tf = 0; tf < 2; tf++)
#pragma unroll
    for (int df = 0; df < 4; df++)
#pragma unroll
      for (int r = 0; r < 4; r++) {
        int trow = th * 32 + tf * 16 + l4 * 4 + r;
        int tok = trow * 2 + grp;   // position within segment (PERM order)
        O[tok * 64 + df * 16 + l15] = (bf16_t)oacc[tf][df][r];
      }
  __syncthreads();
#pragma unroll
  for (int it = 0; it < 4; it++) {
    int c = t + it * 256;
    int tok = c >> 3, c8 = c & 7;
    long j = (long)b * Mtok + perml[tok];  // inverse-permute == scatter to PERM[i]
    *(bf16x8*)(ATT + j * 512 + h * 64 + c8 * 8) = *(const bf16x8*)(O + tok * 64 + c8 * 8);
  }
}

// ---------------------------------------------------------------------------
extern "C" void kernel_launch(void* const* d_in, const int* in_sizes, int n_in,
                              void* d_out, int out_size, void* d_ws, size_t ws_size,
                              hipStream_t stream) {
  const float* q    = (const float*)d_in[0];
  const float* k    = (const float*)d_in[1];
  const float* v    = (const float*)d_in[2];
  const float* Wq   = (const float*)d_in[3];
  const float* Wk   = (const float*)d_in[4];
  const float* Wv   = (const float*)d_in[5];
  const float* Wqkv = (const float*)d_in[6];
  const float* Wout = (const float*)d_in[7];

  char* ws = (char*)d_ws;
  const size_t QKV_BYTES = (size_t)ROWS * 1536 * 2;  // 100,663,296
  const size_t X_BYTES   = (size_t)ROWS * 512 * 2;   //  33,554,432
  bf16_t* QKV   = (bf16_t*)ws;
  bf16_t* X     = (bf16_t*)(ws + QKV_BYTES);          // also ATT (X dead after GEMM2)
  bf16_t* W1t   = (bf16_t*)(ws + QKV_BYTES + X_BYTES);
  bf16_t* Wqkvt = W1t + 512 * 1536;
  bf16_t* Woutt = Wqkvt + 1536 * 512;
  int*    perm  = (int*)(Woutt + 512 * 512);

  k_perm<<<64, 256, 0, stream>>>(perm);
  k_prep_w<<<512, 256, 0, stream>>>(Wq, Wk, Wv, Wqkv, Wout, W1t, Wqkvt, Woutt);
  // GEMM1 (fused f32->bf16): X = [q|k|v] @ W1 (M=32768, N=512, K=1536)
  k_gemm1f<<<dim3(2, 128), 512, 0, stream>>>(q, k, v, W1t, X, 512);
  // GEMM2: QKV = X @ Wqkv (N=1536, K=512)
  k_gemm256<false><<<dim3(6, 128), 512, 0, stream>>>(X, Wqkvt, QKV, nullptr, 1536, 512);
  // attention: reads QKV, writes ATT (aliases X)
  k_attn<<<dim3(128, 8, 2), 256, 0, stream>>>(QKV, perm, X);
  // GEMM3: out = ATT @ Wout (f32 output)
  k_gemm256<true><<<dim3(2, 128), 512, 0, stream>>>(X, Woutt, nullptr, (float*)d_out, 512, 512);
}